// Round 1
// baseline (79.810 us; speedup 1.0000x reference)
//
#include <hip/hip_runtime.h>
#include <math.h>

// MaskedSoftmax: rows=4096, cols=8192, fp32 input, int32 {0,1} mask, fp32 out.
// Row-wise softmax over entries where mask==1; unmasked -> 0; fully-masked row -> 0.

constexpr int ROWS  = 4096;
constexpr int COLS  = 8192;
constexpr int BLOCK = 256;            // multiple of 64 (wave size)
constexpr int V4    = COLS / BLOCK / 4;  // 8 float4 loads per thread (32 elems)

__device__ __forceinline__ float wave_reduce_max(float v) {
    #pragma unroll
    for (int off = 32; off > 0; off >>= 1)
        v = fmaxf(v, __shfl_xor(v, off));
    return v;
}

__device__ __forceinline__ float wave_reduce_sum(float v) {
    #pragma unroll
    for (int off = 32; off > 0; off >>= 1)
        v += __shfl_xor(v, off);
    return v;
}

__global__ __launch_bounds__(BLOCK) void masked_softmax_kernel(
        const float* __restrict__ x,
        const int*   __restrict__ mask,
        float*       __restrict__ out) {
    const int row = blockIdx.x;
    const size_t base = (size_t)row * COLS;
    const float4* __restrict__ xr = reinterpret_cast<const float4*>(x + base);
    const int4*   __restrict__ mr = reinterpret_cast<const int4*>(mask + base);
    float4*       __restrict__ orow = reinterpret_cast<float4*>(out + base);

    const int tid  = threadIdx.x;
    const int lane = tid & 63;
    const int wid  = tid >> 6;   // 4 waves per block

    // ---- Load 32 elements + mask bits into registers, compute local masked max
    float v[V4][4];
    unsigned int mbits = 0;       // bit (i*4+j) = mask of element j of vector i
    float lmax = -INFINITY;

    #pragma unroll
    for (int i = 0; i < V4; ++i) {
        const int idx = i * BLOCK + tid;         // coalesced: lane-contiguous float4s
        const float4 xv = xr[idx];
        const int4   mv = mr[idx];
        v[i][0] = xv.x; v[i][1] = xv.y; v[i][2] = xv.z; v[i][3] = xv.w;
        if (mv.x == 1) { mbits |= 1u << (i * 4 + 0); lmax = fmaxf(lmax, xv.x); }
        if (mv.y == 1) { mbits |= 1u << (i * 4 + 1); lmax = fmaxf(lmax, xv.y); }
        if (mv.z == 1) { mbits |= 1u << (i * 4 + 2); lmax = fmaxf(lmax, xv.z); }
        if (mv.w == 1) { mbits |= 1u << (i * 4 + 3); lmax = fmaxf(lmax, xv.w); }
    }

    // ---- Block max reduce: wave shuffle + 4-entry LDS combine
    __shared__ float red_max[BLOCK / 64];
    __shared__ float red_sum[BLOCK / 64];

    const float wmax = wave_reduce_max(lmax);
    if (lane == 0) red_max[wid] = wmax;
    __syncthreads();
    float mx = fmaxf(fmaxf(red_max[0], red_max[1]), fmaxf(red_max[2], red_max[3]));
    // fully-masked row guard (mx stays -inf): reference uses mx_safe = 0
    const float mx_safe = isinf(mx) ? 0.0f : mx;

    // ---- Compute e = exp(x - mx) where masked, accumulate local sum
    float lsum = 0.0f;
    #pragma unroll
    for (int i = 0; i < V4; ++i) {
        #pragma unroll
        for (int j = 0; j < 4; ++j) {
            const bool m = (mbits >> (i * 4 + j)) & 1u;
            const float e = m ? __expf(v[i][j] - mx_safe) : 0.0f;
            v[i][j] = e;
            lsum += e;
        }
    }

    // ---- Block sum reduce
    const float wsum = wave_reduce_sum(lsum);
    if (lane == 0) red_sum[wid] = wsum;
    __syncthreads();
    const float s = (red_sum[0] + red_sum[1]) + (red_sum[2] + red_sum[3]);
    const float inv = (s == 0.0f) ? 1.0f : (1.0f / s);

    // ---- Write out
    #pragma unroll
    for (int i = 0; i < V4; ++i) {
        const int idx = i * BLOCK + tid;
        float4 o;
        o.x = v[i][0] * inv;
        o.y = v[i][1] * inv;
        o.z = v[i][2] * inv;
        o.w = v[i][3] * inv;
        orow[idx] = o;
    }
}

extern "C" void kernel_launch(void* const* d_in, const int* in_sizes, int n_in,
                              void* d_out, int out_size, void* d_ws, size_t ws_size,
                              hipStream_t stream) {
    const float* x    = (const float*)d_in[0];
    const int*   mask = (const int*)d_in[1];
    float*       out  = (float*)d_out;
    masked_softmax_kernel<<<ROWS, BLOCK, 0, stream>>>(x, mask, out);
}

// Round 3
// 63.048 us; speedup vs baseline: 1.2659x; 1.2659x over previous
//
#include <hip/hip_runtime.h>
#include <math.h>

// MaskedSoftmax: rows=4096, cols=8192, fp32 input, int32 {0,1} mask, fp32 out.
// Row-wise softmax over entries where mask==1; unmasked -> 0; fully-masked row -> 0.
//
// R1 insight: inputs (256 MiB) exactly fit the 256 MiB Infinity Cache, but
// output writes (128 MiB) thrash it. Use non-temporal stores so replayed
// iterations read inputs from L3 instead of HBM.
// R2 fix: __builtin_nontemporal_store needs a clang ext_vector type, not
// HIP's float4 class.

constexpr int ROWS  = 4096;
constexpr int COLS  = 8192;
constexpr int BLOCK = 256;               // multiple of 64 (wave size)
constexpr int V4    = COLS / BLOCK / 4;  // 8 float4 loads per thread (32 elems)

typedef float f32x4 __attribute__((ext_vector_type(4)));

__device__ __forceinline__ float wave_reduce_max(float v) {
    #pragma unroll
    for (int off = 32; off > 0; off >>= 1)
        v = fmaxf(v, __shfl_xor(v, off));
    return v;
}

__device__ __forceinline__ float wave_reduce_sum(float v) {
    #pragma unroll
    for (int off = 32; off > 0; off >>= 1)
        v += __shfl_xor(v, off);
    return v;
}

__global__ __launch_bounds__(BLOCK) void masked_softmax_kernel(
        const float* __restrict__ x,
        const int*   __restrict__ mask,
        float*       __restrict__ out) {
    const int row = blockIdx.x;
    const size_t base = (size_t)row * COLS;
    const float4* __restrict__ xr = reinterpret_cast<const float4*>(x + base);
    const int4*   __restrict__ mr = reinterpret_cast<const int4*>(mask + base);
    f32x4*        __restrict__ orow = reinterpret_cast<f32x4*>(out + base);

    const int tid  = threadIdx.x;
    const int lane = tid & 63;
    const int wid  = tid >> 6;   // 4 waves per block

    // ---- Load 32 elements + mask bits into registers, compute local masked max
    float v[V4][4];
    unsigned int mbits = 0;       // bit (i*4+j) = mask of element j of vector i
    float lmax = -INFINITY;

    #pragma unroll
    for (int i = 0; i < V4; ++i) {
        const int idx = i * BLOCK + tid;         // coalesced: lane-contiguous float4s
        const float4 xv = xr[idx];
        const int4   mv = mr[idx];
        v[i][0] = xv.x; v[i][1] = xv.y; v[i][2] = xv.z; v[i][3] = xv.w;
        if (mv.x == 1) { mbits |= 1u << (i * 4 + 0); lmax = fmaxf(lmax, xv.x); }
        if (mv.y == 1) { mbits |= 1u << (i * 4 + 1); lmax = fmaxf(lmax, xv.y); }
        if (mv.z == 1) { mbits |= 1u << (i * 4 + 2); lmax = fmaxf(lmax, xv.z); }
        if (mv.w == 1) { mbits |= 1u << (i * 4 + 3); lmax = fmaxf(lmax, xv.w); }
    }

    // ---- Block max reduce: wave shuffle + 4-entry LDS combine
    __shared__ float red_max[BLOCK / 64];
    __shared__ float red_sum[BLOCK / 64];

    const float wmax = wave_reduce_max(lmax);
    if (lane == 0) red_max[wid] = wmax;
    __syncthreads();
    float mx = fmaxf(fmaxf(red_max[0], red_max[1]), fmaxf(red_max[2], red_max[3]));
    // fully-masked row guard (mx stays -inf): reference uses mx_safe = 0
    const float mx_safe = isinf(mx) ? 0.0f : mx;

    // ---- Compute e = exp(x - mx) where masked, accumulate local sum
    float lsum = 0.0f;
    #pragma unroll
    for (int i = 0; i < V4; ++i) {
        #pragma unroll
        for (int j = 0; j < 4; ++j) {
            const bool m = (mbits >> (i * 4 + j)) & 1u;
            const float e = m ? __expf(v[i][j] - mx_safe) : 0.0f;
            v[i][j] = e;
            lsum += e;
        }
    }

    // ---- Block sum reduce
    const float wsum = wave_reduce_sum(lsum);
    if (lane == 0) red_sum[wid] = wsum;
    __syncthreads();
    const float s = (red_sum[0] + red_sum[1]) + (red_sum[2] + red_sum[3]);
    const float inv = (s == 0.0f) ? 1.0f : (1.0f / s);

    // ---- Write out with non-temporal (streaming) stores: don't evict the
    // inputs from L3 — they're re-read every graph replay.
    #pragma unroll
    for (int i = 0; i < V4; ++i) {
        const int idx = i * BLOCK + tid;
        f32x4 o;
        o.x = v[i][0] * inv;
        o.y = v[i][1] * inv;
        o.z = v[i][2] * inv;
        o.w = v[i][3] * inv;
        __builtin_nontemporal_store(o, &orow[idx]);
    }
}

extern "C" void kernel_launch(void* const* d_in, const int* in_sizes, int n_in,
                              void* d_out, int out_size, void* d_ws, size_t ws_size,
                              hipStream_t stream) {
    const float* x    = (const float*)d_in[0];
    const int*   mask = (const int*)d_in[1];
    float*       out  = (float*)d_out;
    masked_softmax_kernel<<<ROWS, BLOCK, 0, stream>>>(x, mask, out);
}